// Round 5
// baseline (115.315 us; speedup 1.0000x reference)
//
#include <hip/hip_runtime.h>

// Inputs/outputs are fp32 STORAGE (values bf16-quantized by the harness).
// Proven in R2: the fp32 instantiation passed (absmax = 1 output ulp).

#define HW_ 65536

// device-global scratch — rewritten fully every call; cross-kernel
// visibility via kernel-boundary ordering (R2-proven).
__device__ double g_part[256];
__device__ double g_WgP[32];
__device__ double g_bgP[8];
__device__ float  g_WgPf[32];   // fp32 copies for the SGPR fast path
__device__ float  g_bgPf[8];
__device__ __align__(16) float g_Wm[8192];   // [b*8+gr][o][j] collapsed 64x4 weights
__device__ __align__(16) float g_Bm[2048];   // [b*8+gr][o]    collapsed bias

typedef float f4v __attribute__((ext_vector_type(4)));
typedef float f2v __attribute__((ext_vector_type(2)));

// ---------------------------------------------------------------------------
// K1: per-(b,ch) plane sums of raw inputs (fp64). 16 planes x 16 chunks
// = 256 blocks (1/CU, full-chip read pull).
// ---------------------------------------------------------------------------
__global__ void k_sum(const float* __restrict__ rgb, const float* __restrict__ edge) {
    int plane = blockIdx.x;              // b*4 + ch (ch 3 == edge)
    int chunk = blockIdx.y;              // 0..15
    int b = plane >> 2, ch = plane & 3;
    const float* src = (ch < 3) ? rgb + (size_t)(b * 3 + ch) * HW_
                                : edge + (size_t)b * HW_;
    src += chunk * 4096;
    int t = threadIdx.x;
    double s = 0.0;
    #pragma unroll
    for (int p = 0; p < 4; ++p) {
        float4 v = ((const float4*)src)[p * 256 + t];
        s += (double)v.x + (double)v.y + (double)v.z + (double)v.w;
    }
    #pragma unroll
    for (int off = 32; off; off >>= 1) s += __shfl_down(s, off);
    __shared__ double wsum[4];
    if ((t & 63) == 0) wsum[t >> 6] = s;
    __syncthreads();
    if (t == 0) g_part[plane * 16 + chunk] = wsum[0] + wsum[1] + wsum[2] + wsum[3];
}

// ---------------------------------------------------------------------------
// K2: fused params. grid 32 = b*8+gr, 256 threads.
// tt-dots and block-0 guide-collapse dots are lane-parallel + shuffle-reduce
// (were 64-iter serial fp64 chains on the critical path).
// ---------------------------------------------------------------------------
__global__ void k_params(const float* __restrict__ W1, const float* __restrict__ b1,
                         const float* __restrict__ Wk1, const float* __restrict__ bk1,
                         const float* __restrict__ Wk2, const float* __restrict__ bk2,
                         const float* __restrict__ Wg, const float* __restrict__ bg) {
    int blk = blockIdx.x;          // b*8 + gr
    int b = blk >> 3, gr = blk & 7;
    int t = threadIdx.x;           // 0..255
    int w = t >> 6, l = t & 63;    // wave, lane
    __shared__ double xm[16];
    __shared__ double gsh[64];
    __shared__ double tt_sh[8];
    __shared__ double red[4][64][5];   // cq partials: aw0..aw3, ab

    if (t < 16) {
        double s = 0;
        #pragma unroll
        for (int i = 0; i < 16; ++i) s += g_part[t * 16 + i];
        xm[t] = s * (1.0 / 65536.0);
    }
    __syncthreads();
    if (t < 64) {   // g[b][c] for own b only
        double acc = (double)b1[t];
        #pragma unroll
        for (int j = 0; j < 4; ++j) acc += (double)W1[t * 4 + j] * xm[b * 4 + j];
        gsh[t] = acc;
    }
    __syncthreads();
    // t-values for own (b, gr): 8 dots of length 64, 2 per wave, lane-parallel
    #pragma unroll
    for (int q = 0; q < 2; ++q) {
        int jj = w * 2 + q;                 // 0..7
        int j = gr * 8 + jj;
        double prod = (double)Wk1[j * 64 + l] * gsh[l];
        #pragma unroll
        for (int off = 32; off; off >>= 1) prod += __shfl_down(prod, off);
        if (l == 0) tt_sh[jj] = 1.0 / (1.0 + exp(-(prod + (double)bk1[j])));
    }
    if (blk == 0) {  // collapsed guide weights: 40 dots, wave-parallel
        for (int d = w; d < 40; d += 4) {
            double prod;
            if (d < 32) prod = (double)Wg[(d >> 2) * 64 + l] * (double)W1[l * 4 + (d & 3)];
            else        prod = (double)Wg[(d - 32) * 64 + l] * (double)b1[l];
            #pragma unroll
            for (int off = 32; off; off >>= 1) prod += __shfl_down(prod, off);
            if (l == 0) {
                if (d < 32) { g_WgP[d] = prod; g_WgPf[d] = (float)prod; }
                else {
                    double a = (double)bg[d - 32] + prod;
                    g_bgP[d - 32] = a; g_bgPf[d - 32] = (float)a;
                }
            }
        }
    }
    __syncthreads();

    int o = t & 63, cq = t >> 6;
    double tt[8];
    #pragma unroll
    for (int i = 0; i < 8; ++i) tt[i] = tt_sh[i];
    double aw0 = 0, aw1 = 0, aw2 = 0, aw3 = 0, ab = 0;
    const float* wk2p = Wk2 + ((size_t)gr * 4096 + o * 64) * 8;
    const float* bk2p = bk2 + (size_t)gr * 4096 + o * 64;
    for (int c = cq * 16; c < cq * 16 + 16; ++c) {
        double ker = (double)bk2p[c];
        #pragma unroll
        for (int i = 0; i < 8; ++i)
            ker += tt[i] * (double)wk2p[c * 8 + i];
        aw0 += ker * (double)W1[c * 4 + 0];
        aw1 += ker * (double)W1[c * 4 + 1];
        aw2 += ker * (double)W1[c * 4 + 2];
        ab  += ker * (double)b1[c];
        aw3 += ker * (double)W1[c * 4 + 3];
    }
    red[cq][o][0] = aw0; red[cq][o][1] = aw1; red[cq][o][2] = aw2;
    red[cq][o][3] = aw3; red[cq][o][4] = ab;
    __syncthreads();
    if (t < 64) {
        double w0 = 0, w1 = 0, w2 = 0, w3 = 0, bb = 0;
        #pragma unroll
        for (int q = 0; q < 4; ++q) {
            w0 += red[q][t][0]; w1 += red[q][t][1]; w2 += red[q][t][2];
            w3 += red[q][t][3]; bb += red[q][t][4];
        }
        float* wv = g_Wm + ((size_t)blk * 64 + t) * 4;
        wv[0] = (float)w0; wv[1] = (float)w1; wv[2] = (float)w2; wv[3] = (float)w3;
        g_Bm[blk * 64 + t] = (float)bb;
    }
}

// ---------------------------------------------------------------------------
// K3: per-pixel guide argmax + collapsed 64x4 matvec.
// z=4 channel quarters x 2 px/thread -> grid(128,4,4) = 2048 blocks
// (6/CU via launch_bounds). vs R4 (z=8, 4px): same block count but input
// re-read factor halves (134 -> 67 MB of L2/L3 traffic layered on the
// 67 MB HBM write stream). Guide weights wave-uniform -> SGPRs via
// readfirstlane; input loads issued before LDS staging (latency hides).
// LDS: W stride 68 (region r base bank 4r), bias stride 20 (banks
// {0,20,8,28,16,4,24,12}) — R3-proven conflict-free for 8-way region
// divergence, 16B-aligned per region.
// ---------------------------------------------------------------------------
__launch_bounds__(256, 6)
__global__ void k_main(const float* __restrict__ rgb, const float* __restrict__ edge,
                       float* __restrict__ out) {
    __shared__ __align__(16) float sW[8 * 68];
    __shared__ __align__(16) float sB[8 * 20];
    __shared__ double sWg[32];
    __shared__ double sBg[8];
    int t = threadIdx.x;
    int b = blockIdx.y;
    int z = blockIdx.z;            // channel quarter: channels [z*16, z*16+16)

    // ---- issue input loads FIRST (latency overlaps staging + barrier) ----
    int pxb = (blockIdx.x * 256 + t) * 2;
    f2v v0 = *(const f2v*)(rgb  + (size_t)(b * 3 + 0) * HW_ + pxb);
    f2v v1 = *(const f2v*)(rgb  + (size_t)(b * 3 + 1) * HW_ + pxb);
    f2v v2 = *(const f2v*)(rgb  + (size_t)(b * 3 + 2) * HW_ + pxb);
    f2v v3 = *(const f2v*)(edge + (size_t)b * HW_ + pxb);

    {   // stage this (batch, channel-quarter)'s collapsed kernels
        if (t < 128) {
            int r = t >> 4, ol = t & 15;
            *(float4*)&sW[r * 68 + ol * 4] =
                ((const float4*)g_Wm)[(size_t)(b * 8 + r) * 64 + z * 16 + ol];
        } else {
            int idx = t - 128;
            int r = idx >> 4, ol = idx & 15;
            sB[r * 20 + ol] = g_Bm[(size_t)(b * 8 + r) * 64 + z * 16 + ol];
        }
        if (t < 32) sWg[t] = g_WgP[t];
        else if (t < 40) sBg[t - 32] = g_bgP[t - 32];
    }
    __syncthreads();

    // guide weights: wave-uniform -> SGPRs (readfirstlane), zero VGPR cost
    float wg[32], bgf[8];
    #pragma unroll
    for (int i = 0; i < 32; ++i)
        wg[i] = __int_as_float(__builtin_amdgcn_readfirstlane(__float_as_int(g_WgPf[i])));
    #pragma unroll
    for (int r = 0; r < 8; ++r)
        bgf[r] = __int_as_float(__builtin_amdgcn_readfirstlane(__float_as_int(g_bgPf[r])));

    float xa[2], xb[2], xc[2], xd[2];
    xa[0] = v0.x; xa[1] = v0.y;
    xb[0] = v1.x; xb[1] = v1.y;
    xc[0] = v2.x; xc[1] = v2.y;
    xd[0] = v3.x; xd[1] = v3.y;

    // region argmax: fp32 fast path, fp64 refine on near-ties (first-max wins)
    int reg[2];
    #pragma unroll
    for (int p = 0; p < 2; ++p) {
        float m1 = -1e30f, m2 = -1e30f; int bi = 0;
        #pragma unroll
        for (int r = 0; r < 8; ++r) {
            float gv = bgf[r] + wg[r * 4 + 0] * xa[p] + wg[r * 4 + 1] * xb[p]
                              + wg[r * 4 + 2] * xc[p] + wg[r * 4 + 3] * xd[p];
            if (gv > m1) { m2 = m1; m1 = gv; bi = r; }
            else if (gv > m2) { m2 = gv; }
        }
        if (m1 - m2 < 1e-4f) {
            double da = xa[p], db = xb[p], dc = xc[p], dd = xd[p];
            double bm = -1e300; bi = 0;
            #pragma unroll
            for (int r = 0; r < 8; ++r) {
                double gv = sBg[r] + sWg[r * 4 + 0] * da + sWg[r * 4 + 1] * db
                                   + sWg[r * 4 + 2] * dc + sWg[r * 4 + 3] * dd;
                if (gv > bm) { bm = gv; bi = r; }
            }
        }
        reg[p] = bi;
    }

    int base[2], bbase[2];
    #pragma unroll
    for (int p = 0; p < 2; ++p) { base[p] = reg[p] * 68; bbase[p] = reg[p] * 20; }

    float* outp = out + (size_t)(b * 64 + z * 16) * HW_ + pxb;
    #pragma unroll
    for (int oq = 0; oq < 4; ++oq) {
        float res[4][2];                       // [k within quad][px]
        #pragma unroll
        for (int p = 0; p < 2; ++p) {
            float4 bq = *(const float4*)&sB[bbase[p] + oq * 4];
            float bqa[4] = {bq.x, bq.y, bq.z, bq.w};
            #pragma unroll
            for (int k = 0; k < 4; ++k) {
                float4 wv = *(const float4*)&sW[base[p] + (oq * 4 + k) * 4];
                res[k][p] = bqa[k] + wv.x * xa[p] + wv.y * xb[p]
                                   + wv.z * xc[p] + wv.w * xd[p];
            }
        }
        #pragma unroll
        for (int k = 0; k < 4; ++k) {
            // output is write-once, never re-read in-kernel -> nontemporal
            f2v pk; pk.x = res[k][0]; pk.y = res[k][1];
            __builtin_nontemporal_store(pk, (f2v*)(outp + (size_t)(oq * 4 + k) * HW_));
        }
    }
}

// ---------------------------------------------------------------------------
extern "C" void kernel_launch(void* const* d_in, const int* in_sizes, int n_in,
                              void* d_out, int out_size, void* d_ws, size_t ws_size,
                              hipStream_t stream) {
    (void)d_ws; (void)ws_size;
    const float* rgb  = (const float*)d_in[0];
    const float* edge = (const float*)d_in[1];
    const float* W1   = (const float*)d_in[2];
    const float* b1   = (const float*)d_in[3];
    const float* Wk1  = (const float*)d_in[4];
    const float* bk1  = (const float*)d_in[5];
    const float* Wk2  = (const float*)d_in[6];
    const float* bk2  = (const float*)d_in[7];
    const float* Wg   = (const float*)d_in[8];
    const float* bg   = (const float*)d_in[9];
    float* out = (float*)d_out;

    k_sum<<<dim3(16, 16), 256, 0, stream>>>(rgb, edge);
    k_params<<<32, 256, 0, stream>>>(W1, b1, Wk1, bk1, Wk2, bk2, Wg, bg);
    k_main<<<dim3(128, 4, 4), 256, 0, stream>>>(rgb, edge, out);
}